// Round 8
// baseline (302.043 us; speedup 1.0000x reference)
//
#include <hip/hip_runtime.h>

#define SEQ 4096
#define EMB 1024
#define HS 64
#define PLDA 72   // padded LDS row (shorts)

typedef __attribute__((ext_vector_type(8))) short bf16x8;
typedef __attribute__((ext_vector_type(4))) float f32x4;

__device__ __forceinline__ unsigned short f2b(float f) {
    union { float f; unsigned u; } v; v.f = f;
    unsigned r = v.u + 0x7fffu + ((v.u >> 16) & 1u);
    return (unsigned short)(r >> 16);
}
__device__ __forceinline__ float b2f(unsigned short h) {
    union { unsigned u; float f; } v; v.u = ((unsigned)h) << 16;
    return v.f;
}

// ---------- W transpose + cast: Wt[192][1024] bf16; rows 0-63=Q (pre-scaled), 64-127=K, 128-191=V
__global__ __launch_bounds__(256) void wt_kernel(const float* __restrict__ Wq,
                                                 const float* __restrict__ Wk,
                                                 const float* __restrict__ Wv,
                                                 unsigned short* __restrict__ Wt) {
    int id = blockIdx.x * 256 + threadIdx.x;
    int mat = id >> 16;
    int rem = id & 65535;
    int k = rem >> 6;
    int n = rem & 63;
    const float* W = (mat == 0) ? Wq : (mat == 1) ? Wk : Wv;
    float scale = (mat == 0) ? 0.125f * 1.44269504f : 1.0f;   // fold 1/sqrt(64)*log2(e) into Q
    Wt[(mat * HS + n) * EMB + k] = f2b(W[k * HS + n] * scale);
}

// ---------- fused QKV projection: block GEMM, 32 rows x 192 cols, 512 blocks (2/CU), reg-prefetch
__global__ __launch_bounds__(256, 2) void proj_kernel(const float* __restrict__ x,
                                                      const unsigned short* __restrict__ Wt,
                                                      unsigned short* __restrict__ Qb,
                                                      unsigned short* __restrict__ Kb,
                                                      unsigned short* __restrict__ Vt) {
    __shared__ unsigned short A_lds[32 * PLDA];    // 4608 B
    __shared__ unsigned short W_lds[192 * PLDA];   // 27648 B
    const int tid = threadIdx.x;
    const int wave = tid >> 6, lane = tid & 63;
    const int col = lane & 15, quad = lane >> 4;
    const int m0 = blockIdx.x * 32;
    const int b = m0 >> 12, t0 = m0 & 4095;

    const int xrow = tid >> 4;          // 0..15 (+16 per round)
    const int xfc  = (tid & 15) * 4;
    const int wn   = tid >> 3;          // 0..31 (+32 per round)
    const int wcp  = (tid & 7) * 8;

    f32x4 acc[2][3];
    #pragma unroll
    for (int i = 0; i < 2; i++)
        #pragma unroll
        for (int j = 0; j < 3; j++) acc[i][j] = (f32x4){0.f, 0.f, 0.f, 0.f};

    float4 xr[2];
    bf16x8 wr[6];
    #pragma unroll
    for (int i = 0; i < 2; i++)
        xr[i] = *(const float4*)(x + (size_t)(m0 + i * 16 + xrow) * EMB + xfc);
    #pragma unroll
    for (int i = 0; i < 6; i++)
        wr[i] = *(const bf16x8*)(Wt + (size_t)(i * 32 + wn) * EMB + wcp);

    #pragma unroll 1
    for (int k0 = 0; k0 < EMB; k0 += 64) {
        __syncthreads();
        #pragma unroll
        for (int i = 0; i < 2; i++) {
            ushort4 bb;
            bb.x = f2b(xr[i].x); bb.y = f2b(xr[i].y);
            bb.z = f2b(xr[i].z); bb.w = f2b(xr[i].w);
            *(ushort4*)&A_lds[(i * 16 + xrow) * PLDA + xfc] = bb;
        }
        #pragma unroll
        for (int i = 0; i < 6; i++)
            *(bf16x8*)&W_lds[(i * 32 + wn) * PLDA + wcp] = wr[i];
        __syncthreads();
        if (k0 + 64 < EMB) {
            #pragma unroll
            for (int i = 0; i < 2; i++)
                xr[i] = *(const float4*)(x + (size_t)(m0 + i * 16 + xrow) * EMB + k0 + 64 + xfc);
            #pragma unroll
            for (int i = 0; i < 6; i++)
                wr[i] = *(const bf16x8*)(Wt + (size_t)(i * 32 + wn) * EMB + k0 + 64 + wcp);
        }
        #pragma unroll
        for (int kc = 0; kc < 2; kc++) {
            bf16x8 af[2], bfr[3];
            #pragma unroll
            for (int mt = 0; mt < 2; mt++)
                af[mt] = *(const bf16x8*)&A_lds[(mt * 16 + col) * PLDA + kc * 32 + quad * 8];
            #pragma unroll
            for (int nt = 0; nt < 3; nt++)
                bfr[nt] = *(const bf16x8*)&W_lds[(wave * 48 + nt * 16 + col) * PLDA + kc * 32 + quad * 8];
            #pragma unroll
            for (int mt = 0; mt < 2; mt++)
                #pragma unroll
                for (int nt = 0; nt < 3; nt++)
                    acc[mt][nt] = __builtin_amdgcn_mfma_f32_16x16x32_bf16(af[mt], bfr[nt], acc[mt][nt], 0, 0, 0);
        }
    }

    #pragma unroll
    for (int mt = 0; mt < 2; mt++)
        #pragma unroll
        for (int nt = 0; nt < 3; nt++) {
            const int g = wave * 3 + nt;       // 0..11
            const int mat = g >> 2;            // 0=Q 1=K 2=V (wave-uniform)
            const int ncol = (g & 3) * 16 + col;
            #pragma unroll
            for (int r = 0; r < 4; r++) {
                unsigned short val = f2b(acc[mt][nt][r]);
                int row = mt * 16 + quad * 4 + r;
                if (mat == 0)      Qb[(size_t)(m0 + row) * HS + ncol] = val;
                else if (mat == 1) Kb[(size_t)(m0 + row) * HS + ncol] = val;
                else               Vt[((size_t)b * HS + ncol) * SEQ + t0 + row] = val;
            }
        }
}

// ---------- flash attention step (templated on causal-mask need) ----------
template<bool MASK>
__device__ __forceinline__ void attn_step(int s, int s_end, int ns, int q0,
                                          int col, int quad,
                                          const unsigned short* Kp,
                                          const unsigned short* Vp,
                                          const bf16x8 qf[2],
                                          bf16x8 kf[4][2],
                                          f32x4 o[4], float l[4],
                                          unsigned short* P_lds) {
    const int kv0 = s << 6;
    f32x4 sacc[4];
    #pragma unroll
    for (int ct = 0; ct < 4; ct++) sacc[ct] = (f32x4){0.f, 0.f, 0.f, 0.f};
    #pragma unroll
    for (int ct = 0; ct < 4; ct++)
        #pragma unroll
        for (int c = 0; c < 2; c++)
            sacc[ct] = __builtin_amdgcn_mfma_f32_16x16x32_bf16(qf[c], kf[ct][c], sacc[ct], 0, 0, 0);

    bf16x8 vf[4][2];
    #pragma unroll
    for (int ct = 0; ct < 4; ct++) {
        const unsigned short* vp = Vp + (size_t)(ct * 16 + col) * SEQ + kv0 + quad * 8;
        vf[ct][0] = *(const bf16x8*)(vp);
        vf[ct][1] = *(const bf16x8*)(vp + 32);
    }
    if (s + 1 < s_end) {
        #pragma unroll
        for (int ct = 0; ct < 4; ct++) {
            const unsigned short* kp = Kp + (size_t)(((s + 1) << 6) + ct * 16 + col) * HS + quad * 8;
            kf[ct][0] = *(const bf16x8*)(kp);
            kf[ct][1] = *(const bf16x8*)(kp + 32);
        }
    }

    float p[4][4];
    #pragma unroll
    for (int ct = 0; ct < 4; ct++) {
        int cg = kv0 + ct * 16 + col;
        #pragma unroll
        for (int r = 0; r < 4; r++) {
            float e = __builtin_exp2f(sacc[ct][r]);
            if (MASK) {
                int rg = q0 + quad * 4 + r;
                e = (cg > rg) ? 0.f : e;
            }
            p[ct][r] = e;
            l[r] += e;
        }
    }

    #pragma unroll
    for (int ct = 0; ct < 4; ct++)
        #pragma unroll
        for (int r = 0; r < 4; r++)
            P_lds[(quad * 4 + r) * 72 + ct * 16 + col] = f2b(p[ct][r]);
    bf16x8 pf[2];
    #pragma unroll
    for (int c = 0; c < 2; c++)
        pf[c] = *(const bf16x8*)&P_lds[col * 72 + quad * 8 + c * 32];

    #pragma unroll
    for (int ct = 0; ct < 4; ct++)
        #pragma unroll
        for (int c = 0; c < 2; c++)
            o[ct] = __builtin_amdgcn_mfma_f32_16x16x32_bf16(pf[c], vf[ct][c], o[ct], 0, 0, 0);
}

// ---------- flash attention (causal), split-KV x6, 4 wave-tasks per 256-thread block ----------
__global__ __launch_bounds__(256, 6) void attn_kernel(const unsigned short* __restrict__ Qb,
                                                      const unsigned short* __restrict__ Kb,
                                                      const unsigned short* __restrict__ Vt,
                                                      unsigned short* __restrict__ Opart,
                                                      float* __restrict__ Lpart) {
    __shared__ unsigned short P_lds[4][16 * 72];
    const int tid = threadIdx.x;
    const int wave = tid >> 6, lane = tid & 63;
    const int col = lane & 15, quad = lane >> 4;
    const int w = blockIdx.x * 4 + wave;   // 0..6143
    const int split = w % 6;
    const int rest = w / 6;                // 0..1023
    const int b = rest & 3;
    const int tile = 255 - (rest >> 2);    // longest-first
    const int q0 = tile * 16;
    const size_t qrow = (size_t)(b << 12) + q0;

    const int ns = (q0 + 79) >> 6;
    const int s_beg = (ns * split) / 6;
    const int s_end = (ns * (split + 1)) / 6;

    bf16x8 qf[2];
    #pragma unroll
    for (int c = 0; c < 2; c++)
        qf[c] = *(const bf16x8*)(Qb + (qrow + col) * HS + quad * 8 + c * 32);

    f32x4 o[4];
    float l[4];
    #pragma unroll
    for (int ct = 0; ct < 4; ct++) o[ct] = (f32x4){0.f, 0.f, 0.f, 0.f};
    #pragma unroll
    for (int r = 0; r < 4; r++) l[r] = 0.f;

    const unsigned short* Kp = Kb + ((size_t)(b << 12)) * HS;
    const unsigned short* Vp = Vt + (size_t)b * HS * SEQ;
    unsigned short* Pl = P_lds[wave];

    if (s_beg < s_end) {
        bf16x8 kf[4][2];
        #pragma unroll
        for (int ct = 0; ct < 4; ct++) {
            const unsigned short* kp = Kp + (size_t)((s_beg << 6) + ct * 16 + col) * HS + quad * 8;
            kf[ct][0] = *(const bf16x8*)(kp);
            kf[ct][1] = *(const bf16x8*)(kp + 32);
        }
        const int hot_end = (s_end == ns) ? ns - 1 : s_end;
        for (int s = s_beg; s < hot_end; s++)
            attn_step<false>(s, s_end, ns, q0, col, quad, Kp, Vp, qf, kf, o, l, Pl);
        if (s_end == ns)
            attn_step<true>(ns - 1, s_end, ns, q0, col, quad, Kp, Vp, qf, kf, o, l, Pl);
    }

    #pragma unroll
    for (int off = 1; off < 16; off <<= 1)
        #pragma unroll
        for (int r = 0; r < 4; r++)
            l[r] += __shfl_xor(l[r], off, 64);

    // bf16 partials, contiguous: Opart[idx][ct*256 + lane*4 + e]
    unsigned short* Op = Opart + (size_t)w * 1024;
    #pragma unroll
    for (int ct = 0; ct < 4; ct++) {
        ushort4 st;
        st.x = f2b(o[ct][0]); st.y = f2b(o[ct][1]);
        st.z = f2b(o[ct][2]); st.w = f2b(o[ct][3]);
        *(ushort4*)(Op + ct * 256 + lane * 4) = st;
    }
    if (col == 0) {
        #pragma unroll
        for (int r = 0; r < 4; r++)
            Lpart[w * 16 + quad * 4 + r] = l[r];
    }
}

// ---------- combine split-KV partials ----------
__global__ __launch_bounds__(256) void comb_kernel(const unsigned short* __restrict__ Opart,
                                                   const float* __restrict__ Lpart,
                                                   float* __restrict__ out) {
    int gid = blockIdx.x * 256 + threadIdx.x;   // 262144
    int row = gid >> 4;                          // 0..16383
    int c4 = (gid & 15) * 4;
    int b = row >> 12;
    int t = row & 4095;
    int tile = t >> 4, rin = t & 15;
    int quad = rin >> 2, r = rin & 3;
    int ct = c4 >> 4, col0 = c4 & 15;
    int rest = ((255 - tile) << 2) | b;

    float acc[4] = {0.f, 0.f, 0.f, 0.f};
    float l = 0.f;
    #pragma unroll
    for (int s = 0; s < 6; s++) {
        int idx = rest * 6 + s;
        const unsigned short* base = Opart + (size_t)idx * 1024 + ct * 256;
        #pragma unroll
        for (int j = 0; j < 4; j++)
            acc[j] += b2f(base[(quad * 16 + col0 + j) * 4 + r]);
        l += Lpart[idx * 16 + rin];
    }
    float inv = 1.f / l;
    float4 res = make_float4(acc[0] * inv, acc[1] * inv, acc[2] * inv, acc[3] * inv);
    *(float4*)(out + (size_t)row * HS + c4) = res;
}

extern "C" void kernel_launch(void* const* d_in, const int* in_sizes, int n_in,
                              void* d_out, int out_size, void* d_ws, size_t ws_size,
                              hipStream_t stream) {
    const float* x  = (const float*)d_in[0];
    const float* Wk = (const float*)d_in[1];
    const float* Wq = (const float*)d_in[2];
    const float* Wv = (const float*)d_in[3];
    float* out = (float*)d_out;

    char* ws = (char*)d_ws;
    unsigned short* Wt = (unsigned short*)(ws);                 // 393216 B
    unsigned short* Qb = (unsigned short*)(ws + 393216);        // 2 MiB
    unsigned short* Kb = (unsigned short*)(ws + 2490368);       // 2 MiB
    unsigned short* Vt = (unsigned short*)(ws + 4587520);       // 2 MiB
    unsigned short* Opart = (unsigned short*)(ws + 6684672);    // 6144*1024*2 = 12.58 MB
    float* Lpart          = (float*)(ws + 19267584);            // 6144*16*4 = 393216 B -> end 19.66 MB

    wt_kernel<<<dim3(768), dim3(256), 0, stream>>>(Wq, Wk, Wv, Wt);
    proj_kernel<<<dim3(512), dim3(256), 0, stream>>>(x, Wt, Qb, Kb, Vt);
    attn_kernel<<<dim3(1536), dim3(256), 0, stream>>>(Qb, Kb, Vt, Opart, Lpart);
    comb_kernel<<<dim3(1024), dim3(256), 0, stream>>>(Opart, Lpart, out);
}

// Round 9
// 193.997 us; speedup vs baseline: 1.5569x; 1.5569x over previous
//
#include <hip/hip_runtime.h>

#define SEQ 4096
#define EMB 1024
#define HS 64

typedef __attribute__((ext_vector_type(8))) short bf16x8;
typedef __attribute__((ext_vector_type(4))) float f32x4;

__device__ __forceinline__ unsigned short f2b(float f) {
    union { float f; unsigned u; } v; v.f = f;
    unsigned r = v.u + 0x7fffu + ((v.u >> 16) & 1u);
    return (unsigned short)(r >> 16);
}
__device__ __forceinline__ float b2f(unsigned short h) {
    union { unsigned u; float f; } v; v.u = ((unsigned)h) << 16;
    return v.f;
}
// async global->LDS DMA, 16B per lane; LDS dst = wave-uniform base + lane*16
template <typename T>
__device__ __forceinline__ void gll16(const T* g, void* l) {
    __builtin_amdgcn_global_load_lds(
        (const __attribute__((address_space(1))) unsigned int*)(g),
        (__attribute__((address_space(3))) unsigned int*)(l), 16, 0, 0);
}

// ---------- W transpose + cast: Wt[192][1024] bf16; rows 0-63=Q (pre-scaled), 64-127=K, 128-191=V
__global__ __launch_bounds__(256) void wt_kernel(const float* __restrict__ Wq,
                                                 const float* __restrict__ Wk,
                                                 const float* __restrict__ Wv,
                                                 unsigned short* __restrict__ Wt) {
    int id = blockIdx.x * 256 + threadIdx.x;
    int mat = id >> 16;
    int rem = id & 65535;
    int k = rem >> 6;
    int n = rem & 63;
    const float* W = (mat == 0) ? Wq : (mat == 1) ? Wk : Wv;
    float scale = (mat == 0) ? 0.125f * 1.44269504f : 1.0f;   // fold 1/sqrt(64)*log2(e) into Q
    Wt[(mat * HS + n) * EMB + k] = f2b(W[k * HS + n] * scale);
}

// ---------- fused QKV projection: 32 rows x 192 cols, LDS staging via global_load_lds DMA ----------
// x tile LDS[32][64] fp32, 16B-chunk XOR swizzle: LDS chunk c of row r holds src chunk c^(r&15)
// W tile LDS[192][64] bf16, 16B-chunk XOR swizzle: LDS chunk c of row r holds src chunk c^(r&7)
__global__ __launch_bounds__(256, 2) void proj_kernel(const float* __restrict__ x,
                                                      const unsigned short* __restrict__ Wt,
                                                      unsigned short* __restrict__ Qb,
                                                      unsigned short* __restrict__ Kb,
                                                      unsigned short* __restrict__ Vt) {
    __shared__ float xf[32 * 64];               // 8 KiB
    __shared__ unsigned short wb[192 * 64];     // 24 KiB
    const int tid = threadIdx.x;
    const int wave = tid >> 6, lane = tid & 63;
    const int col = lane & 15, quad = lane >> 4;
    const int m0 = blockIdx.x * 32;
    const int b = m0 >> 12, t0 = m0 & 4095;

    f32x4 acc[2][3];
    #pragma unroll
    for (int i = 0; i < 2; i++)
        #pragma unroll
        for (int j = 0; j < 3; j++) acc[i][j] = (f32x4){0.f, 0.f, 0.f, 0.f};

    // per-lane swizzled source offsets (row-invariant parts)
    const int xrow_in = lane >> 4;      // 0..3 within a 4-row DMA instr
    const int xc = lane & 15;           // 16B chunk within 64-float row
    const int wrow_in = lane >> 3;      // 0..7 within an 8-row DMA instr
    const int wc = lane & 7;            // 16B chunk within 64-short row

    #pragma unroll 1
    for (int k0 = 0; k0 < EMB; k0 += 64) {
        __syncthreads();   // previous iteration's LDS readers done
        // x: 2 DMA instrs/wave, 4 rows each
        #pragma unroll
        for (int j = 0; j < 2; j++) {
            int row = wave * 8 + j * 4 + xrow_in;
            int sc = xc ^ (row & 15);
            gll16(x + (size_t)(m0 + row) * EMB + k0 + sc * 4, &xf[(wave * 8 + j * 4) * 64]);
        }
        // Wt: 6 DMA instrs/wave, 8 rows each
        #pragma unroll
        for (int j = 0; j < 6; j++) {
            int row = wave * 48 + j * 8 + wrow_in;
            int sc = wc ^ (row & 7);
            gll16(Wt + (size_t)row * EMB + k0 + sc * 8, &wb[(wave * 48 + j * 8) * 64]);
        }
        __syncthreads();   // DMA landed (vmcnt drained by barrier)

        #pragma unroll
        for (int kc = 0; kc < 2; kc++) {
            const int q2 = quad + kc * 4;           // 32B group index 0..7
            bf16x8 af[2], bfr[3];
            #pragma unroll
            for (int mt = 0; mt < 2; mt++) {
                int rr = mt * 16 + col;             // rr&15 == col
                float4 lo = *(const float4*)&xf[rr * 64 + ((2 * q2) ^ col) * 4];
                float4 hi = *(const float4*)&xf[rr * 64 + ((2 * q2 + 1) ^ col) * 4];
                bf16x8 a;
                a[0] = (short)f2b(lo.x); a[1] = (short)f2b(lo.y);
                a[2] = (short)f2b(lo.z); a[3] = (short)f2b(lo.w);
                a[4] = (short)f2b(hi.x); a[5] = (short)f2b(hi.y);
                a[6] = (short)f2b(hi.z); a[7] = (short)f2b(hi.w);
                af[mt] = a;
            }
            #pragma unroll
            for (int nt = 0; nt < 3; nt++) {
                int rn = wave * 48 + nt * 16 + col; // rn&7 == col&7
                bfr[nt] = *(const bf16x8*)&wb[rn * 64 + (q2 ^ (col & 7)) * 8];
            }
            #pragma unroll
            for (int mt = 0; mt < 2; mt++)
                #pragma unroll
                for (int nt = 0; nt < 3; nt++)
                    acc[mt][nt] = __builtin_amdgcn_mfma_f32_16x16x32_bf16(af[mt], bfr[nt], acc[mt][nt], 0, 0, 0);
        }
    }

    #pragma unroll
    for (int mt = 0; mt < 2; mt++)
        #pragma unroll
        for (int nt = 0; nt < 3; nt++) {
            const int g = wave * 3 + nt;       // 0..11
            const int mat = g >> 2;            // 0=Q 1=K 2=V (wave-uniform)
            const int ncol = (g & 3) * 16 + col;
            #pragma unroll
            for (int r = 0; r < 4; r++) {
                unsigned short val = f2b(acc[mt][nt][r]);
                int row = mt * 16 + quad * 4 + r;
                if (mat == 0)      Qb[(size_t)(m0 + row) * HS + ncol] = val;
                else if (mat == 1) Kb[(size_t)(m0 + row) * HS + ncol] = val;
                else               Vt[((size_t)b * HS + ncol) * SEQ + t0 + row] = val;
            }
        }
}

// ---------- flash attention step (templated on causal-mask need) ----------
template<bool MASK>
__device__ __forceinline__ void attn_step(int s, int s_end, int ns, int q0,
                                          int col, int quad,
                                          const unsigned short* Kp,
                                          const unsigned short* Vp,
                                          const bf16x8 qf[2],
                                          bf16x8 kf[4][2],
                                          f32x4 o[4], float l[4],
                                          unsigned short* P_lds) {
    const int kv0 = s << 6;
    f32x4 sacc[4];
    #pragma unroll
    for (int ct = 0; ct < 4; ct++) sacc[ct] = (f32x4){0.f, 0.f, 0.f, 0.f};
    #pragma unroll
    for (int ct = 0; ct < 4; ct++)
        #pragma unroll
        for (int c = 0; c < 2; c++)
            sacc[ct] = __builtin_amdgcn_mfma_f32_16x16x32_bf16(qf[c], kf[ct][c], sacc[ct], 0, 0, 0);

    bf16x8 vf[4][2];
    #pragma unroll
    for (int ct = 0; ct < 4; ct++) {
        const unsigned short* vp = Vp + (size_t)(ct * 16 + col) * SEQ + kv0 + quad * 8;
        vf[ct][0] = *(const bf16x8*)(vp);
        vf[ct][1] = *(const bf16x8*)(vp + 32);
    }
    if (s + 1 < s_end) {
        #pragma unroll
        for (int ct = 0; ct < 4; ct++) {
            const unsigned short* kp = Kp + (size_t)(((s + 1) << 6) + ct * 16 + col) * HS + quad * 8;
            kf[ct][0] = *(const bf16x8*)(kp);
            kf[ct][1] = *(const bf16x8*)(kp + 32);
        }
    }

    float p[4][4];
    #pragma unroll
    for (int ct = 0; ct < 4; ct++) {
        int cg = kv0 + ct * 16 + col;
        #pragma unroll
        for (int r = 0; r < 4; r++) {
            float e = __builtin_exp2f(sacc[ct][r]);
            if (MASK) {
                int rg = q0 + quad * 4 + r;
                e = (cg > rg) ? 0.f : e;
            }
            p[ct][r] = e;
            l[r] += e;
        }
    }

    #pragma unroll
    for (int ct = 0; ct < 4; ct++)
        #pragma unroll
        for (int r = 0; r < 4; r++)
            P_lds[(quad * 4 + r) * 72 + ct * 16 + col] = f2b(p[ct][r]);
    bf16x8 pf[2];
    #pragma unroll
    for (int c = 0; c < 2; c++)
        pf[c] = *(const bf16x8*)&P_lds[col * 72 + quad * 8 + c * 32];

    #pragma unroll
    for (int ct = 0; ct < 4; ct++)
        #pragma unroll
        for (int c = 0; c < 2; c++)
            o[ct] = __builtin_amdgcn_mfma_f32_16x16x32_bf16(pf[c], vf[ct][c], o[ct], 0, 0, 0);
}

// ---------- flash attention (causal), split-KV x6, one wave per (tile, split) ----------
__global__ __launch_bounds__(64, 4) void attn_kernel(const unsigned short* __restrict__ Qb,
                                                     const unsigned short* __restrict__ Kb,
                                                     const unsigned short* __restrict__ Vt,
                                                     unsigned short* __restrict__ Opart,
                                                     float* __restrict__ Lpart) {
    __shared__ unsigned short P_lds[16 * 72];
    const int lane = threadIdx.x;
    const int col = lane & 15, quad = lane >> 4;
    const int w = blockIdx.x;              // 0..6143
    const int split = w % 6;
    const int rest = w / 6;                // 0..1023
    const int b = rest & 3;
    const int tile = 255 - (rest >> 2);    // longest-first
    const int q0 = tile * 16;
    const size_t qrow = (size_t)(b << 12) + q0;

    const int ns = (q0 + 79) >> 6;
    const int s_beg = (ns * split) / 6;
    const int s_end = (ns * (split + 1)) / 6;

    bf16x8 qf[2];
    #pragma unroll
    for (int c = 0; c < 2; c++)
        qf[c] = *(const bf16x8*)(Qb + (qrow + col) * HS + quad * 8 + c * 32);

    f32x4 o[4];
    float l[4];
    #pragma unroll
    for (int ct = 0; ct < 4; ct++) o[ct] = (f32x4){0.f, 0.f, 0.f, 0.f};
    #pragma unroll
    for (int r = 0; r < 4; r++) l[r] = 0.f;

    const unsigned short* Kp = Kb + ((size_t)(b << 12)) * HS;
    const unsigned short* Vp = Vt + (size_t)b * HS * SEQ;

    if (s_beg < s_end) {
        bf16x8 kf[4][2];
        #pragma unroll
        for (int ct = 0; ct < 4; ct++) {
            const unsigned short* kp = Kp + (size_t)((s_beg << 6) + ct * 16 + col) * HS + quad * 8;
            kf[ct][0] = *(const bf16x8*)(kp);
            kf[ct][1] = *(const bf16x8*)(kp + 32);
        }
        const int hot_end = (s_end == ns) ? ns - 1 : s_end;
        for (int s = s_beg; s < hot_end; s++)
            attn_step<false>(s, s_end, ns, q0, col, quad, Kp, Vp, qf, kf, o, l, P_lds);
        if (s_end == ns)
            attn_step<true>(ns - 1, s_end, ns, q0, col, quad, Kp, Vp, qf, kf, o, l, P_lds);
    }

    #pragma unroll
    for (int off = 1; off < 16; off <<= 1)
        #pragma unroll
        for (int r = 0; r < 4; r++)
            l[r] += __shfl_xor(l[r], off, 64);

    // bf16 partials, contiguous 512B stores: Opart[w][ct*256 + lane*4]
    unsigned short* Op = Opart + (size_t)w * 1024;
    #pragma unroll
    for (int ct = 0; ct < 4; ct++) {
        ushort4 st;
        st.x = f2b(o[ct][0]); st.y = f2b(o[ct][1]);
        st.z = f2b(o[ct][2]); st.w = f2b(o[ct][3]);
        *(ushort4*)(Op + ct * 256 + lane * 4) = st;
    }
    if (col == 0) {
        #pragma unroll
        for (int r = 0; r < 4; r++)
            Lpart[w * 16 + quad * 4 + r] = l[r];
    }
}

// ---------- combine split-KV partials ----------
__global__ __launch_bounds__(256) void comb_kernel(const unsigned short* __restrict__ Opart,
                                                   const float* __restrict__ Lpart,
                                                   float* __restrict__ out) {
    int gid = blockIdx.x * 256 + threadIdx.x;   // 262144
    int row = gid >> 4;                          // 0..16383
    int c4 = (gid & 15) * 4;
    int b = row >> 12;
    int t = row & 4095;
    int tile = t >> 4, rin = t & 15;
    int quad = rin >> 2, r = rin & 3;
    int ct = c4 >> 4, col0 = c4 & 15;
    int rest = ((255 - tile) << 2) | b;

    float acc[4] = {0.f, 0.f, 0.f, 0.f};
    float l = 0.f;
    #pragma unroll
    for (int s = 0; s < 6; s++) {
        int idx = rest * 6 + s;
        const unsigned short* base = Opart + (size_t)idx * 1024 + ct * 256;
        #pragma unroll
        for (int j = 0; j < 4; j++)
            acc[j] += b2f(base[(quad * 16 + col0 + j) * 4 + r]);
        l += Lpart[idx * 16 + rin];
    }
    float inv = 1.f / l;
    float4 res = make_float4(acc[0] * inv, acc[1] * inv, acc[2] * inv, acc[3] * inv);
    *(float4*)(out + (size_t)row * HS + c4) = res;
}

extern "C" void kernel_launch(void* const* d_in, const int* in_sizes, int n_in,
                              void* d_out, int out_size, void* d_ws, size_t ws_size,
                              hipStream_t stream) {
    const float* x  = (const float*)d_in[0];
    const float* Wk = (const float*)d_in[1];
    const float* Wq = (const float*)d_in[2];
    const float* Wv = (const float*)d_in[3];
    float* out = (float*)d_out;

    char* ws = (char*)d_ws;
    unsigned short* Wt = (unsigned short*)(ws);                 // 393216 B
    unsigned short* Qb = (unsigned short*)(ws + 393216);        // 2 MiB
    unsigned short* Kb = (unsigned short*)(ws + 2490368);       // 2 MiB
    unsigned short* Vt = (unsigned short*)(ws + 4587520);       // 2 MiB
    unsigned short* Opart = (unsigned short*)(ws + 6684672);    // 6144*1024*2 = 12.58 MB
    float* Lpart          = (float*)(ws + 19267584);            // 6144*16*4 = 393216 B

    wt_kernel<<<dim3(768), dim3(256), 0, stream>>>(Wq, Wk, Wv, Wt);
    proj_kernel<<<dim3(512), dim3(256), 0, stream>>>(x, Wt, Qb, Kb, Vt);
    attn_kernel<<<dim3(6144), dim3(64), 0, stream>>>(Qb, Kb, Vt, Opart, Lpart);
    comb_kernel<<<dim3(1024), dim3(256), 0, stream>>>(Opart, Lpart, out);
}

// Round 10
// 162.334 us; speedup vs baseline: 1.8606x; 1.1951x over previous
//
#include <hip/hip_runtime.h>

#define SEQ 4096
#define EMB 1024
#define HS 64

typedef __attribute__((ext_vector_type(8))) short bf16x8;
typedef __attribute__((ext_vector_type(4))) float f32x4;

__device__ __forceinline__ unsigned short f2b(float f) {
    union { float f; unsigned u; } v; v.f = f;
    unsigned r = v.u + 0x7fffu + ((v.u >> 16) & 1u);
    return (unsigned short)(r >> 16);
}
__device__ __forceinline__ float b2f(unsigned short h) {
    union { unsigned u; float f; } v; v.u = ((unsigned)h) << 16;
    return v.f;
}
// async global->LDS DMA, 16B/lane; LDS dst = wave-uniform base + lane*16
template <typename T>
__device__ __forceinline__ void gll16(const T* g, void* l) {
    __builtin_amdgcn_global_load_lds(
        (const __attribute__((address_space(1))) unsigned int*)(g),
        (__attribute__((address_space(3))) unsigned int*)(l), 16, 0, 0);
}

// ---------- W transpose + cast: Wt[192][1024] bf16; rows 0-63=Q (pre-scaled), 64-127=K, 128-191=V
__global__ __launch_bounds__(256) void wt_kernel(const float* __restrict__ Wq,
                                                 const float* __restrict__ Wk,
                                                 const float* __restrict__ Wv,
                                                 unsigned short* __restrict__ Wt) {
    int id = blockIdx.x * 256 + threadIdx.x;
    int mat = id >> 16;
    int rem = id & 65535;
    int k = rem >> 6;
    int n = rem & 63;
    const float* W = (mat == 0) ? Wq : (mat == 1) ? Wk : Wv;
    float scale = (mat == 0) ? 0.125f * 1.44269504f : 1.0f;   // fold 1/sqrt(64)*log2(e) into Q
    Wt[(mat * HS + n) * EMB + k] = f2b(W[k * HS + n] * scale);
}

// ---------- fused QKV projection: 32 rows x 192 cols, double-buffered DMA staging ----------
// x tile LDS[32][64] fp32, 16B-chunk XOR swizzle c^(row&15); W tile LDS[192][64] bf16, c^(row&7)
__global__ __launch_bounds__(256, 2) void proj_kernel(const float* __restrict__ x,
                                                      const unsigned short* __restrict__ Wt,
                                                      unsigned short* __restrict__ Qb,
                                                      unsigned short* __restrict__ Kb,
                                                      unsigned short* __restrict__ Vt) {
    __shared__ float xf[2][32 * 64];              // 2 x 8 KiB
    __shared__ unsigned short wb[2][192 * 64];    // 2 x 24 KiB
    const int tid = threadIdx.x;
    const int wave = tid >> 6, lane = tid & 63;
    const int col = lane & 15, quad = lane >> 4;
    const int m0 = blockIdx.x * 32;
    const int b = m0 >> 12, t0 = m0 & 4095;

    const int xr_in = lane >> 4;        // 0..3 rows within one x DMA instr
    const int xc = lane & 15;           // 16B chunk within 256B x row
    const int wr_in = lane >> 3;        // 0..7 rows within one W DMA instr
    const int wc = lane & 7;            // 16B chunk within 128B W row

    f32x4 acc[2][3];
    #pragma unroll
    for (int i = 0; i < 2; i++)
        #pragma unroll
        for (int j = 0; j < 3; j++) acc[i][j] = (f32x4){0.f, 0.f, 0.f, 0.f};

    auto stage = [&](int k0, int bufi) {
        #pragma unroll
        for (int t = 0; t < 2; t++) {
            int R = (wave + t * 4) * 4;          // x rows R..R+3
            int row = R + xr_in;
            gll16(x + (size_t)(m0 + row) * EMB + k0 + ((xc ^ (row & 15)) << 2),
                  &xf[bufi][R * 64]);
        }
        #pragma unroll
        for (int t = 0; t < 6; t++) {
            int R = (wave * 6 + t) * 8;          // W rows R..R+7
            int row = R + wr_in;
            gll16(Wt + (size_t)row * EMB + k0 + ((wc ^ (row & 7)) << 3),
                  &wb[bufi][R * 64]);
        }
    };

    stage(0, 0);
    int buf = 0;
    #pragma unroll 1
    for (int k0 = 0; k0 < EMB; k0 += 64) {
        __syncthreads();                 // DMA for buf landed; prev readers of buf^1 done
        if (k0 + 64 < EMB) stage(k0 + 64, buf ^ 1);
        #pragma unroll
        for (int kc = 0; kc < 2; kc++) {
            const int q2 = quad + kc * 4;        // 32B group 0..7
            bf16x8 af[2], bfr[3];
            #pragma unroll
            for (int mt = 0; mt < 2; mt++) {
                int rr = mt * 16 + col;          // rr&15 == col
                float4 lo = *(const float4*)&xf[buf][rr * 64 + (((2 * q2) ^ col) << 2)];
                float4 hi = *(const float4*)&xf[buf][rr * 64 + (((2 * q2 + 1) ^ col) << 2)];
                bf16x8 a;
                a[0] = (short)f2b(lo.x); a[1] = (short)f2b(lo.y);
                a[2] = (short)f2b(lo.z); a[3] = (short)f2b(lo.w);
                a[4] = (short)f2b(hi.x); a[5] = (short)f2b(hi.y);
                a[6] = (short)f2b(hi.z); a[7] = (short)f2b(hi.w);
                af[mt] = a;
            }
            #pragma unroll
            for (int nt = 0; nt < 3; nt++) {
                int rn = wave * 48 + nt * 16 + col;  // rn&7 == col&7
                bfr[nt] = *(const bf16x8*)&wb[buf][rn * 64 + ((q2 ^ (col & 7)) << 3)];
            }
            #pragma unroll
            for (int mt = 0; mt < 2; mt++)
                #pragma unroll
                for (int nt = 0; nt < 3; nt++)
                    acc[mt][nt] = __builtin_amdgcn_mfma_f32_16x16x32_bf16(af[mt], bfr[nt], acc[mt][nt], 0, 0, 0);
        }
        buf ^= 1;
    }

    #pragma unroll
    for (int mt = 0; mt < 2; mt++)
        #pragma unroll
        for (int nt = 0; nt < 3; nt++) {
            const int g = wave * 3 + nt;       // 0..11
            const int mat = g >> 2;            // 0=Q 1=K 2=V (wave-uniform)
            const int ncol = (g & 3) * 16 + col;
            #pragma unroll
            for (int r = 0; r < 4; r++) {
                unsigned short val = f2b(acc[mt][nt][r]);
                int row = mt * 16 + quad * 4 + r;
                if (mat == 0)      Qb[(size_t)(m0 + row) * HS + ncol] = val;
                else if (mat == 1) Kb[(size_t)(m0 + row) * HS + ncol] = val;
                else               Vt[((size_t)b * HS + ncol) * SEQ + t0 + row] = val;
            }
        }
}

// ---------- flash attention (causal): 4-wave blocks, BM=64, dbuf DMA-staged K/V, split-KV <=8 steps
__global__ __launch_bounds__(256, 3) void attn_kernel(const unsigned short* __restrict__ Qb,
                                                      const unsigned short* __restrict__ Kb,
                                                      const unsigned short* __restrict__ Vt,
                                                      unsigned short* __restrict__ Opart,
                                                      float* __restrict__ Lpart) {
    __shared__ unsigned short Kl[2][64 * 64];   // 2 x 8 KiB, swizzled c^(row&7)
    __shared__ unsigned short Vl[2][64 * 64];   // 2 x 8 KiB, swizzled c^(h&7)
    __shared__ unsigned short P_lds[4][16 * 72];
    const int tid = threadIdx.x;
    const int wave = tid >> 6, lane = tid & 63;
    const int col = lane & 15, quad = lane >> 4;
    const int bid = blockIdx.x;            // 0..1151
    const int g = 287 - (bid >> 2);        // longest-first piece id
    const int b = bid & 3;
    // decode g -> (T = 64-row q tile, piece)
    int T = 0, accp = 0;
    for (;;) { int np = (T + 8) >> 3; if (accp + np > g) break; accp += np; T++; }
    const int piece = g - accp;
    const int q0 = T << 6;
    const int s_beg = piece << 3;
    const int s_end = min(s_beg + 8, T + 1);

    const unsigned short* Kp = Kb + ((size_t)(b << 12)) * HS;
    const unsigned short* Vp = Vt + (size_t)b * HS * SEQ;

    bf16x8 qf[2];
    #pragma unroll
    for (int c = 0; c < 2; c++)
        qf[c] = *(const bf16x8*)(Qb + ((size_t)(b << 12) + q0 + wave * 16 + col) * HS + quad * 8 + c * 32);

    f32x4 o[4];
    float l[4];
    #pragma unroll
    for (int ct = 0; ct < 4; ct++) o[ct] = (f32x4){0.f, 0.f, 0.f, 0.f};
    #pragma unroll
    for (int r = 0; r < 4; r++) l[r] = 0.f;

    const int r_in = lane >> 3;   // 0..7 rows within one DMA instr
    const int ch = lane & 7;      // 16B chunk within 128B row

    auto stage = [&](int s, int bufi) {
        const int kv0 = s << 6;
        #pragma unroll
        for (int t = 0; t < 2; t++) {
            int R = (wave + t * 4) * 8;          // rows R..R+7
            int row = R + r_in;
            gll16(Kp + (size_t)(kv0 + row) * HS + ((ch ^ (row & 7)) << 3), &Kl[bufi][R * 64]);
            gll16(Vp + (size_t)row * SEQ + kv0 + ((ch ^ (row & 7)) << 3), &Vl[bufi][R * 64]);
        }
    };

    stage(s_beg, 0);
    int buf = 0;
    const int rgb = q0 + wave * 16 + quad * 4;   // mask row base (+r)
    unsigned short* Pl = P_lds[wave];

    #pragma unroll 1
    for (int s = s_beg; s < s_end; s++) {
        __syncthreads();                 // DMA(buf) landed; prev readers of buf^1 done
        if (s + 1 < s_end) stage(s + 1, buf ^ 1);
        const int kv0 = s << 6;

        f32x4 sacc[4];
        #pragma unroll
        for (int ct = 0; ct < 4; ct++) sacc[ct] = (f32x4){0.f, 0.f, 0.f, 0.f};
        #pragma unroll
        for (int ct = 0; ct < 4; ct++) {
            int n = ct * 16 + col;
            #pragma unroll
            for (int kc = 0; kc < 2; kc++) {
                bf16x8 kf = *(const bf16x8*)&Kl[buf][n * 64 + (((kc * 4 + quad) ^ (col & 7)) << 3)];
                sacc[ct] = __builtin_amdgcn_mfma_f32_16x16x32_bf16(qf[kc], kf, sacc[ct], 0, 0, 0);
            }
        }

        // max-free softmax (scale folded into Q); mask is inert for s < T
        float p[4][4];
        #pragma unroll
        for (int ct = 0; ct < 4; ct++) {
            int cg = kv0 + ct * 16 + col;
            #pragma unroll
            for (int r = 0; r < 4; r++) {
                float e = __builtin_exp2f(sacc[ct][r]);
                e = (cg > rgb + r) ? 0.f : e;
                p[ct][r] = e;
                l[r] += e;
            }
        }

        // P: C-layout -> wave-private LDS -> A-layout
        #pragma unroll
        for (int ct = 0; ct < 4; ct++)
            #pragma unroll
            for (int r = 0; r < 4; r++)
                Pl[(quad * 4 + r) * 72 + ct * 16 + col] = f2b(p[ct][r]);
        bf16x8 pf[2];
        #pragma unroll
        for (int c = 0; c < 2; c++)
            pf[c] = *(const bf16x8*)&Pl[col * 72 + quad * 8 + c * 32];

        #pragma unroll
        for (int ct = 0; ct < 4; ct++) {
            int h = ct * 16 + col;
            #pragma unroll
            for (int kc = 0; kc < 2; kc++) {
                bf16x8 vf = *(const bf16x8*)&Vl[buf][h * 64 + (((kc * 4 + quad) ^ (col & 7)) << 3)];
                o[ct] = __builtin_amdgcn_mfma_f32_16x16x32_bf16(pf[kc], vf, o[ct], 0, 0, 0);
            }
        }
        buf ^= 1;
    }

    #pragma unroll
    for (int off = 1; off < 16; off <<= 1)
        #pragma unroll
        for (int r = 0; r < 4; r++)
            l[r] += __shfl_xor(l[r], off, 64);

    // bf16 partials: Opart[(bid*4+wave)][ct*256 + lane*4 + r]
    unsigned short* Op = Opart + ((size_t)bid * 4 + wave) * 1024;
    #pragma unroll
    for (int ct = 0; ct < 4; ct++) {
        ushort4 st;
        st.x = f2b(o[ct][0]); st.y = f2b(o[ct][1]);
        st.z = f2b(o[ct][2]); st.w = f2b(o[ct][3]);
        *(ushort4*)(Op + ct * 256 + lane * 4) = st;
    }
    if (col == 0) {
        #pragma unroll
        for (int r = 0; r < 4; r++)
            Lpart[bid * 64 + wave * 16 + quad * 4 + r] = l[r];
    }
}

// ---------- combine split-KV partials (variable piece count per tile) ----------
__global__ __launch_bounds__(256) void comb_kernel(const unsigned short* __restrict__ Opart,
                                                   const float* __restrict__ Lpart,
                                                   float* __restrict__ out) {
    int gid = blockIdx.x * 256 + threadIdx.x;   // 262144
    int row = gid >> 4;                          // 0..16383
    int c4 = (gid & 15) * 4;
    int b = row >> 12;
    int t = row & 4095;
    int T = t >> 6;
    int rin = t & 63;
    int wv = rin >> 4;
    int r16 = rin & 15;
    int quad = r16 >> 2, rr = r16 & 3;
    int ct = c4 >> 4, col0 = c4 & 15;
    int qq = T >> 3, rm = T & 7;
    int base = T + ((qq * (qq - 1)) << 2) + rm * qq;   // prefix of piece counts
    int np = (T + 8) >> 3;

    float acc[4] = {0.f, 0.f, 0.f, 0.f};
    float l = 0.f;
    for (int p = 0; p < np; p++) {
        int gg = base + p;
        int idx = ((287 - gg) << 2) | b;   // bid
        const unsigned short* bs = Opart + ((size_t)idx * 4 + wv) * 1024 + ct * 256;
        #pragma unroll
        for (int j = 0; j < 4; j++)
            acc[j] += b2f(bs[(quad * 16 + col0 + j) * 4 + rr]);
        l += Lpart[idx * 64 + rin];
    }
    float inv = 1.f / l;
    float4 res = make_float4(acc[0] * inv, acc[1] * inv, acc[2] * inv, acc[3] * inv);
    *(float4*)(out + (size_t)row * HS + c4) = res;
}

extern "C" void kernel_launch(void* const* d_in, const int* in_sizes, int n_in,
                              void* d_out, int out_size, void* d_ws, size_t ws_size,
                              hipStream_t stream) {
    const float* x  = (const float*)d_in[0];
    const float* Wk = (const float*)d_in[1];
    const float* Wq = (const float*)d_in[2];
    const float* Wv = (const float*)d_in[3];
    float* out = (float*)d_out;

    char* ws = (char*)d_ws;
    unsigned short* Wt = (unsigned short*)(ws);                 // 393216 B
    unsigned short* Qb = (unsigned short*)(ws + 393216);        // 2 MiB
    unsigned short* Kb = (unsigned short*)(ws + 2490368);       // 2 MiB
    unsigned short* Vt = (unsigned short*)(ws + 4587520);       // 2 MiB
    unsigned short* Opart = (unsigned short*)(ws + 6684672);    // 1152*4096*2 = 9.44 MB
    float* Lpart          = (float*)(ws + 16121856);            // 1152*64*4 = 294912 B

    wt_kernel<<<dim3(768), dim3(256), 0, stream>>>(Wq, Wk, Wv, Wt);
    proj_kernel<<<dim3(512), dim3(256), 0, stream>>>(x, Wt, Qb, Kb, Vt);
    attn_kernel<<<dim3(1152), dim3(256), 0, stream>>>(Qb, Kb, Vt, Opart, Lpart);
    comb_kernel<<<dim3(1024), dim3(256), 0, stream>>>(Opart, Lpart, out);
}

// Round 11
// 154.698 us; speedup vs baseline: 1.9525x; 1.0494x over previous
//
#include <hip/hip_runtime.h>

#define SEQ 4096
#define EMB 1024
#define HS 64

typedef __attribute__((ext_vector_type(8))) short bf16x8;
typedef __attribute__((ext_vector_type(4))) float f32x4;

__device__ __forceinline__ unsigned short f2b(float f) {
    union { float f; unsigned u; } v; v.f = f;
    unsigned r = v.u + 0x7fffu + ((v.u >> 16) & 1u);
    return (unsigned short)(r >> 16);
}
__device__ __forceinline__ float b2f(unsigned short h) {
    union { unsigned u; float f; } v; v.u = ((unsigned)h) << 16;
    return v.f;
}
// async global->LDS DMA, 16B/lane; LDS dst = wave-uniform base + lane*16
template <typename T>
__device__ __forceinline__ void gll16(const T* g, void* l) {
    __builtin_amdgcn_global_load_lds(
        (const __attribute__((address_space(1))) unsigned int*)(g),
        (__attribute__((address_space(3))) unsigned int*)(l), 16, 0, 0);
}

// ---------- W transpose + cast: Wt[192][1024] bf16; rows 0-63=Q (pre-scaled), 64-127=K, 128-191=V
__global__ __launch_bounds__(256) void wt_kernel(const float* __restrict__ Wq,
                                                 const float* __restrict__ Wk,
                                                 const float* __restrict__ Wv,
                                                 unsigned short* __restrict__ Wt) {
    int id = blockIdx.x * 256 + threadIdx.x;
    int mat = id >> 16;
    int rem = id & 65535;
    int k = rem >> 6;
    int n = rem & 63;
    const float* W = (mat == 0) ? Wq : (mat == 1) ? Wk : Wv;
    float scale = (mat == 0) ? 0.125f * 1.44269504f : 1.0f;   // fold 1/sqrt(64)*log2(e) into Q
    Wt[(mat * HS + n) * EMB + k] = f2b(W[k * HS + n] * scale);
}

// ---------- fused QKV projection: 32 rows x 192 cols, double-buffered DMA staging (R10-proven) ----------
__global__ __launch_bounds__(256, 2) void proj_kernel(const float* __restrict__ x,
                                                      const unsigned short* __restrict__ Wt,
                                                      unsigned short* __restrict__ Qb,
                                                      unsigned short* __restrict__ Kb,
                                                      unsigned short* __restrict__ Vt) {
    __shared__ float xf[2][32 * 64];              // 2 x 8 KiB
    __shared__ unsigned short wb[2][192 * 64];    // 2 x 24 KiB
    const int tid = threadIdx.x;
    const int wave = tid >> 6, lane = tid & 63;
    const int col = lane & 15, quad = lane >> 4;
    const int m0 = blockIdx.x * 32;
    const int b = m0 >> 12, t0 = m0 & 4095;

    const int xr_in = lane >> 4;
    const int xc = lane & 15;
    const int wr_in = lane >> 3;
    const int wc = lane & 7;

    f32x4 acc[2][3];
    #pragma unroll
    for (int i = 0; i < 2; i++)
        #pragma unroll
        for (int j = 0; j < 3; j++) acc[i][j] = (f32x4){0.f, 0.f, 0.f, 0.f};

    auto stage = [&](int k0, int bufi) {
        #pragma unroll
        for (int t = 0; t < 2; t++) {
            int R = (wave + t * 4) * 4;
            int row = R + xr_in;
            gll16(x + (size_t)(m0 + row) * EMB + k0 + ((xc ^ (row & 15)) << 2),
                  &xf[bufi][R * 64]);
        }
        #pragma unroll
        for (int t = 0; t < 6; t++) {
            int R = (wave * 6 + t) * 8;
            int row = R + wr_in;
            gll16(Wt + (size_t)row * EMB + k0 + ((wc ^ (row & 7)) << 3),
                  &wb[bufi][R * 64]);
        }
    };

    stage(0, 0);
    int buf = 0;
    #pragma unroll 1
    for (int k0 = 0; k0 < EMB; k0 += 64) {
        __syncthreads();
        if (k0 + 64 < EMB) stage(k0 + 64, buf ^ 1);
        #pragma unroll
        for (int kc = 0; kc < 2; kc++) {
            const int q2 = quad + kc * 4;
            bf16x8 af[2], bfr[3];
            #pragma unroll
            for (int mt = 0; mt < 2; mt++) {
                int rr = mt * 16 + col;
                float4 lo = *(const float4*)&xf[buf][rr * 64 + (((2 * q2) ^ col) << 2)];
                float4 hi = *(const float4*)&xf[buf][rr * 64 + (((2 * q2 + 1) ^ col) << 2)];
                bf16x8 a;
                a[0] = (short)f2b(lo.x); a[1] = (short)f2b(lo.y);
                a[2] = (short)f2b(lo.z); a[3] = (short)f2b(lo.w);
                a[4] = (short)f2b(hi.x); a[5] = (short)f2b(hi.y);
                a[6] = (short)f2b(hi.z); a[7] = (short)f2b(hi.w);
                af[mt] = a;
            }
            #pragma unroll
            for (int nt = 0; nt < 3; nt++) {
                int rn = wave * 48 + nt * 16 + col;
                bfr[nt] = *(const bf16x8*)&wb[buf][rn * 64 + ((q2 ^ (col & 7)) << 3)];
            }
            #pragma unroll
            for (int mt = 0; mt < 2; mt++)
                #pragma unroll
                for (int nt = 0; nt < 3; nt++)
                    acc[mt][nt] = __builtin_amdgcn_mfma_f32_16x16x32_bf16(af[mt], bfr[nt], acc[mt][nt], 0, 0, 0);
        }
        buf ^= 1;
    }

    #pragma unroll
    for (int mt = 0; mt < 2; mt++)
        #pragma unroll
        for (int nt = 0; nt < 3; nt++) {
            const int g = wave * 3 + nt;
            const int mat = g >> 2;
            const int ncol = (g & 3) * 16 + col;
            #pragma unroll
            for (int r = 0; r < 4; r++) {
                unsigned short val = f2b(acc[mt][nt][r]);
                int row = mt * 16 + quad * 4 + r;
                if (mat == 0)      Qb[(size_t)(m0 + row) * HS + ncol] = val;
                else if (mat == 1) Kb[(size_t)(m0 + row) * HS + ncol] = val;
                else               Vt[((size_t)b * HS + ncol) * SEQ + t0 + row] = val;
            }
        }
}

// ---------- flash attention (causal): 8-wave blocks, BM=128, dbuf DMA K/V, all blocks co-resident
// piece decomposition: tile T (128 rows) has 2T+2 kv-steps, split into np(T)=(T>>2)+1 pieces of <=8
__global__ __launch_bounds__(512, 3) void attn_kernel(const unsigned short* __restrict__ Qb,
                                                      const unsigned short* __restrict__ Kb,
                                                      const unsigned short* __restrict__ Vt,
                                                      unsigned short* __restrict__ Opart,
                                                      float* __restrict__ Lpart) {
    __shared__ unsigned short Kl[2][64 * 64];   // 2 x 8 KiB, chunk swizzle c^(row&7)
    __shared__ unsigned short Vl[2][64 * 64];   // 2 x 8 KiB, chunk swizzle c^(h&7)
    __shared__ unsigned short P_lds[8][16 * 72];
    const int tid = threadIdx.x;
    const int wave = tid >> 6, lane = tid & 63;
    const int col = lane & 15, quad = lane >> 4;
    const int bid = blockIdx.x;            // 0..575
    const int g = 143 - (bid >> 2);        // longest-first piece id
    const int b = bid & 3;
    // decode g -> (T, piece)
    int T = 0, accp = 0;
    for (;;) { int np = (T >> 2) + 1; if (accp + np > g) break; accp += np; T++; }
    const int piece = g - accp;
    const int q0 = T << 7;
    const int s_beg = piece << 3;
    const int s_end = min(s_beg + 8, 2 * T + 2);

    const unsigned short* Kp = Kb + ((size_t)(b << 12)) * HS;
    const unsigned short* Vp = Vt + (size_t)b * HS * SEQ;

    bf16x8 qf[2];
    #pragma unroll
    for (int c = 0; c < 2; c++)
        qf[c] = *(const bf16x8*)(Qb + ((size_t)(b << 12) + q0 + wave * 16 + col) * HS + quad * 8 + c * 32);

    f32x4 o[4];
    float l[4];
    #pragma unroll
    for (int ct = 0; ct < 4; ct++) o[ct] = (f32x4){0.f, 0.f, 0.f, 0.f};
    #pragma unroll
    for (int r = 0; r < 4; r++) l[r] = 0.f;

    const int r_in = lane >> 3;   // 0..7 rows within one DMA instr
    const int ch = lane & 7;      // 16B chunk within 128B row

    auto stage = [&](int s, int bufi) {
        const int kv0 = s << 6;
        int R = wave * 8;                    // this wave's 8 rows
        int row = R + r_in;
        gll16(Kp + (size_t)(kv0 + row) * HS + ((ch ^ (row & 7)) << 3), &Kl[bufi][R * 64]);
        gll16(Vp + (size_t)row * SEQ + kv0 + ((ch ^ (row & 7)) << 3), &Vl[bufi][R * 64]);
    };

    stage(s_beg, 0);
    int buf = 0;
    const int rgb = q0 + wave * 16 + quad * 4;   // mask row base (+r)
    unsigned short* Pl = P_lds[wave];

    #pragma unroll 1
    for (int s = s_beg; s < s_end; s++) {
        __syncthreads();                 // DMA(buf) landed; prev readers of buf^1 done
        if (s + 1 < s_end) stage(s + 1, buf ^ 1);
        const int kv0 = s << 6;

        f32x4 sacc[4];
        #pragma unroll
        for (int ct = 0; ct < 4; ct++) sacc[ct] = (f32x4){0.f, 0.f, 0.f, 0.f};
        #pragma unroll
        for (int ct = 0; ct < 4; ct++) {
            int n = ct * 16 + col;
            #pragma unroll
            for (int kc = 0; kc < 2; kc++) {
                bf16x8 kf = *(const bf16x8*)&Kl[buf][n * 64 + (((kc * 4 + quad) ^ (col & 7)) << 3)];
                sacc[ct] = __builtin_amdgcn_mfma_f32_16x16x32_bf16(qf[kc], kf, sacc[ct], 0, 0, 0);
            }
        }

        // max-free softmax (scale folded into Q); mask inert except at the diagonal
        float p[4][4];
        #pragma unroll
        for (int ct = 0; ct < 4; ct++) {
            int cg = kv0 + ct * 16 + col;
            #pragma unroll
            for (int r = 0; r < 4; r++) {
                float e = __builtin_exp2f(sacc[ct][r]);
                e = (cg > rgb + r) ? 0.f : e;
                p[ct][r] = e;
                l[r] += e;
            }
        }

        // P: C-layout -> wave-private LDS -> A-layout
        #pragma unroll
        for (int ct = 0; ct < 4; ct++)
            #pragma unroll
            for (int r = 0; r < 4; r++)
                Pl[(quad * 4 + r) * 72 + ct * 16 + col] = f2b(p[ct][r]);
        bf16x8 pf[2];
        #pragma unroll
        for (int c = 0; c < 2; c++)
            pf[c] = *(const bf16x8*)&Pl[col * 72 + quad * 8 + c * 32];

        #pragma unroll
        for (int ct = 0; ct < 4; ct++) {
            int h = ct * 16 + col;
            #pragma unroll
            for (int kc = 0; kc < 2; kc++) {
                bf16x8 vf = *(const bf16x8*)&Vl[buf][h * 64 + (((kc * 4 + quad) ^ (col & 7)) << 3)];
                o[ct] = __builtin_amdgcn_mfma_f32_16x16x32_bf16(pf[kc], vf, o[ct], 0, 0, 0);
            }
        }
        buf ^= 1;
    }

    #pragma unroll
    for (int off = 1; off < 16; off <<= 1)
        #pragma unroll
        for (int r = 0; r < 4; r++)
            l[r] += __shfl_xor(l[r], off, 64);

    // bf16 partials: Opart[widx][ct*256 + lane*4 + r]
    const int widx = bid * 8 + wave;
    unsigned short* Op = Opart + (size_t)widx * 1024;
    #pragma unroll
    for (int ct = 0; ct < 4; ct++) {
        ushort4 st;
        st.x = f2b(o[ct][0]); st.y = f2b(o[ct][1]);
        st.z = f2b(o[ct][2]); st.w = f2b(o[ct][3]);
        *(ushort4*)(Op + ct * 256 + lane * 4) = st;
    }
    if (col == 0) {
        #pragma unroll
        for (int r = 0; r < 4; r++)
            Lpart[widx * 16 + quad * 4 + r] = l[r];
    }
}

// ---------- combine split-KV partials: thread layout mirrors attn lanes (coalesced ushort4 reads)
__global__ __launch_bounds__(256) void comb_kernel(const unsigned short* __restrict__ Opart,
                                                   const float* __restrict__ Lpart,
                                                   float* __restrict__ out) {
    const int bid = blockIdx.x;            // 1024 = 4 b x 32 T x 8 wave
    const int b = bid & 3;
    const int T = (bid >> 2) & 31;
    const int wave = bid >> 7;             // 0..7
    const int tid = threadIdx.x;
    const int lane = tid & 63, ct = tid >> 6;
    const int col = lane & 15, quad = lane >> 4;

    const int Q = T >> 2, R = T & 3;
    const int base = T + 2 * Q * (Q - 1) + R * Q;   // piece-id prefix
    const int np = Q + 1;

    float acc[4] = {0.f, 0.f, 0.f, 0.f};
    float l[4] = {0.f, 0.f, 0.f, 0.f};
    for (int p = 0; p < np; p++) {
        int gg = base + p;
        int bidp = ((143 - gg) << 2) | b;
        int widx = bidp * 8 + wave;
        ushort4 v = *(const ushort4*)(Opart + (size_t)widx * 1024 + ct * 256 + lane * 4);
        acc[0] += b2f(v.x); acc[1] += b2f(v.y);
        acc[2] += b2f(v.z); acc[3] += b2f(v.w);
        #pragma unroll
        for (int r = 0; r < 4; r++)
            l[r] += Lpart[widx * 16 + quad * 4 + r];
    }
    const size_t rowb = (size_t)(b << 12) + (T << 7) + wave * 16 + quad * 4;
    #pragma unroll
    for (int r = 0; r < 4; r++)
        out[(rowb + r) * HS + ct * 16 + col] = acc[r] / l[r];
}

extern "C" void kernel_launch(void* const* d_in, const int* in_sizes, int n_in,
                              void* d_out, int out_size, void* d_ws, size_t ws_size,
                              hipStream_t stream) {
    const float* x  = (const float*)d_in[0];
    const float* Wk = (const float*)d_in[1];
    const float* Wq = (const float*)d_in[2];
    const float* Wv = (const float*)d_in[3];
    float* out = (float*)d_out;

    char* ws = (char*)d_ws;
    unsigned short* Wt = (unsigned short*)(ws);                 // 393216 B
    unsigned short* Qb = (unsigned short*)(ws + 393216);        // 2 MiB
    unsigned short* Kb = (unsigned short*)(ws + 2490368);       // 2 MiB
    unsigned short* Vt = (unsigned short*)(ws + 4587520);       // 2 MiB
    unsigned short* Opart = (unsigned short*)(ws + 6684672);    // 4608*1024*2 = 9.44 MB
    float* Lpart          = (float*)(ws + 16121856);            // 4608*16*4 = 294912 B

    wt_kernel<<<dim3(768), dim3(256), 0, stream>>>(Wq, Wk, Wv, Wt);
    proj_kernel<<<dim3(512), dim3(256), 0, stream>>>(x, Wt, Qb, Kb, Vt);
    attn_kernel<<<dim3(576), dim3(512), 0, stream>>>(Qb, Kb, Vt, Opart, Lpart);
    comb_kernel<<<dim3(1024), dim3(256), 0, stream>>>(Opart, Lpart, out);
}

// Round 12
// 152.756 us; speedup vs baseline: 1.9773x; 1.0127x over previous
//
#include <hip/hip_runtime.h>

#define SEQ 4096
#define EMB 1024
#define HS 64

typedef __attribute__((ext_vector_type(8))) short bf16x8;
typedef __attribute__((ext_vector_type(4))) float f32x4;

__device__ __forceinline__ unsigned short f2b(float f) {
    union { float f; unsigned u; } v; v.f = f;
    unsigned r = v.u + 0x7fffu + ((v.u >> 16) & 1u);
    return (unsigned short)(r >> 16);
}
__device__ __forceinline__ float b2f(unsigned short h) {
    union { unsigned u; float f; } v; v.u = ((unsigned)h) << 16;
    return v.f;
}
// async global->LDS DMA, 16B/lane; LDS dst = wave-uniform base + lane*16
template <typename T>
__device__ __forceinline__ void gll16(const T* g, void* l) {
    __builtin_amdgcn_global_load_lds(
        (const __attribute__((address_space(1))) unsigned int*)(g),
        (__attribute__((address_space(3))) unsigned int*)(l), 16, 0, 0);
}

// ---------- W transpose + cast: Wt[192][1024] bf16; rows 0-63=Q (pre-scaled), 64-127=K, 128-191=V
__global__ __launch_bounds__(256) void wt_kernel(const float* __restrict__ Wq,
                                                 const float* __restrict__ Wk,
                                                 const float* __restrict__ Wv,
                                                 unsigned short* __restrict__ Wt) {
    int id = blockIdx.x * 256 + threadIdx.x;
    int mat = id >> 16;
    int rem = id & 65535;
    int k = rem >> 6;
    int n = rem & 63;
    const float* W = (mat == 0) ? Wq : (mat == 1) ? Wk : Wv;
    float scale = (mat == 0) ? 0.125f * 1.44269504f : 1.0f;   // fold 1/sqrt(64)*log2(e) into Q
    Wt[(mat * HS + n) * EMB + k] = f2b(W[k * HS + n] * scale);
}

// ---------- fused QKV projection: 32 rows x 192 cols, double-buffered DMA staging (R10-proven) ----------
__global__ __launch_bounds__(256, 2) void proj_kernel(const float* __restrict__ x,
                                                      const unsigned short* __restrict__ Wt,
                                                      unsigned short* __restrict__ Qb,
                                                      unsigned short* __restrict__ Kb,
                                                      unsigned short* __restrict__ Vt) {
    __shared__ float xf[2][32 * 64];              // 2 x 8 KiB
    __shared__ unsigned short wb[2][192 * 64];    // 2 x 24 KiB
    const int tid = threadIdx.x;
    const int wave = tid >> 6, lane = tid & 63;
    const int col = lane & 15, quad = lane >> 4;
    const int m0 = blockIdx.x * 32;
    const int b = m0 >> 12, t0 = m0 & 4095;

    const int xr_in = lane >> 4;
    const int xc = lane & 15;
    const int wr_in = lane >> 3;
    const int wc = lane & 7;

    f32x4 acc[2][3];
    #pragma unroll
    for (int i = 0; i < 2; i++)
        #pragma unroll
        for (int j = 0; j < 3; j++) acc[i][j] = (f32x4){0.f, 0.f, 0.f, 0.f};

    auto stage = [&](int k0, int bufi) {
        #pragma unroll
        for (int t = 0; t < 2; t++) {
            int R = (wave + t * 4) * 4;
            int row = R + xr_in;
            gll16(x + (size_t)(m0 + row) * EMB + k0 + ((xc ^ (row & 15)) << 2),
                  &xf[bufi][R * 64]);
        }
        #pragma unroll
        for (int t = 0; t < 6; t++) {
            int R = (wave * 6 + t) * 8;
            int row = R + wr_in;
            gll16(Wt + (size_t)row * EMB + k0 + ((wc ^ (row & 7)) << 3),
                  &wb[bufi][R * 64]);
        }
    };

    stage(0, 0);
    int buf = 0;
    #pragma unroll 1
    for (int k0 = 0; k0 < EMB; k0 += 64) {
        __syncthreads();
        if (k0 + 64 < EMB) stage(k0 + 64, buf ^ 1);
        #pragma unroll
        for (int kc = 0; kc < 2; kc++) {
            const int q2 = quad + kc * 4;
            bf16x8 af[2], bfr[3];
            #pragma unroll
            for (int mt = 0; mt < 2; mt++) {
                int rr = mt * 16 + col;
                float4 lo = *(const float4*)&xf[buf][rr * 64 + (((2 * q2) ^ col) << 2)];
                float4 hi = *(const float4*)&xf[buf][rr * 64 + (((2 * q2 + 1) ^ col) << 2)];
                bf16x8 a;
                a[0] = (short)f2b(lo.x); a[1] = (short)f2b(lo.y);
                a[2] = (short)f2b(lo.z); a[3] = (short)f2b(lo.w);
                a[4] = (short)f2b(hi.x); a[5] = (short)f2b(hi.y);
                a[6] = (short)f2b(hi.z); a[7] = (short)f2b(hi.w);
                af[mt] = a;
            }
            #pragma unroll
            for (int nt = 0; nt < 3; nt++) {
                int rn = wave * 48 + nt * 16 + col;
                bfr[nt] = *(const bf16x8*)&wb[buf][rn * 64 + ((q2 ^ (col & 7)) << 3)];
            }
            #pragma unroll
            for (int mt = 0; mt < 2; mt++)
                #pragma unroll
                for (int nt = 0; nt < 3; nt++)
                    acc[mt][nt] = __builtin_amdgcn_mfma_f32_16x16x32_bf16(af[mt], bfr[nt], acc[mt][nt], 0, 0, 0);
        }
        buf ^= 1;
    }

    #pragma unroll
    for (int mt = 0; mt < 2; mt++)
        #pragma unroll
        for (int nt = 0; nt < 3; nt++) {
            const int g = wave * 3 + nt;
            const int mat = g >> 2;
            const int ncol = (g & 3) * 16 + col;
            #pragma unroll
            for (int r = 0; r < 4; r++) {
                unsigned short val = f2b(acc[mt][nt][r]);
                int row = mt * 16 + quad * 4 + r;
                if (mat == 0)      Qb[(size_t)(m0 + row) * HS + ncol] = val;
                else if (mat == 1) Kb[(size_t)(m0 + row) * HS + ncol] = val;
                else               Vt[((size_t)b * HS + ncol) * SEQ + t0 + row] = val;
            }
        }
}

// ---------- flash attention (causal): 8-wave blocks, BM=128, dbuf DMA K/V ----------
// tile T has 2T+2 kv-steps; pieces of <=12 steps; np(T)=(T+6)/6; grid 408 <= 512 resident slots
__global__ __launch_bounds__(512, 4) void attn_kernel(const unsigned short* __restrict__ Qb,
                                                      const unsigned short* __restrict__ Kb,
                                                      const unsigned short* __restrict__ Vt,
                                                      unsigned short* __restrict__ Opart,
                                                      float* __restrict__ Lpart) {
    __shared__ unsigned short Kl[2][64 * 64];   // 2 x 8 KiB, chunk swizzle c^(row&7)
    __shared__ unsigned short Vl[2][64 * 64];   // 2 x 8 KiB, chunk swizzle c^(h&7)
    __shared__ unsigned short P_lds[8][16 * 72];
    const int tid = threadIdx.x;
    const int wave = tid >> 6, lane = tid & 63;
    const int col = lane & 15, quad = lane >> 4;
    const int bid = blockIdx.x;            // 0..407
    const int g = 101 - (bid >> 2);        // longest-first piece id
    const int b = bid & 3;
    // decode g -> (T, piece)
    int T = 0, accp = 0;
    for (;;) { int np = (T + 6) / 6; if (accp + np > g) break; accp += np; T++; }
    const int piece = g - accp;
    const int q0 = T << 7;
    const int s_beg = piece * 12;
    const int s_end = min(s_beg + 12, 2 * T + 2);

    const unsigned short* Kp = Kb + ((size_t)(b << 12)) * HS;
    const unsigned short* Vp = Vt + (size_t)b * HS * SEQ;

    bf16x8 qf[2];
    #pragma unroll
    for (int c = 0; c < 2; c++)
        qf[c] = *(const bf16x8*)(Qb + ((size_t)(b << 12) + q0 + wave * 16 + col) * HS + quad * 8 + c * 32);

    f32x4 o[4];
    float l[4];
    #pragma unroll
    for (int ct = 0; ct < 4; ct++) o[ct] = (f32x4){0.f, 0.f, 0.f, 0.f};
    #pragma unroll
    for (int r = 0; r < 4; r++) l[r] = 0.f;

    const int r_in = lane >> 3;   // 0..7 rows within one DMA instr
    const int ch = lane & 7;      // 16B chunk within 128B row

    auto stage = [&](int s, int bufi) {
        const int kv0 = s << 6;
        int R = wave * 8;                    // this wave's 8 rows
        int row = R + r_in;
        gll16(Kp + (size_t)(kv0 + row) * HS + ((ch ^ (row & 7)) << 3), &Kl[bufi][R * 64]);
        gll16(Vp + (size_t)row * SEQ + kv0 + ((ch ^ (row & 7)) << 3), &Vl[bufi][R * 64]);
    };

    stage(s_beg, 0);
    int buf = 0;
    const int rgb = q0 + wave * 16 + quad * 4;   // mask row base (+r)
    unsigned short* Pl = P_lds[wave];

    #pragma unroll 1
    for (int s = s_beg; s < s_end; s++) {
        __syncthreads();                 // DMA(buf) landed; prev readers of buf^1 done
        if (s + 1 < s_end) stage(s + 1, buf ^ 1);
        const int kv0 = s << 6;

        f32x4 sacc[4];
        #pragma unroll
        for (int ct = 0; ct < 4; ct++) sacc[ct] = (f32x4){0.f, 0.f, 0.f, 0.f};
        #pragma unroll
        for (int ct = 0; ct < 4; ct++) {
            int n = ct * 16 + col;
            #pragma unroll
            for (int kc = 0; kc < 2; kc++) {
                bf16x8 kf = *(const bf16x8*)&Kl[buf][n * 64 + (((kc * 4 + quad) ^ (col & 7)) << 3)];
                sacc[ct] = __builtin_amdgcn_mfma_f32_16x16x32_bf16(qf[kc], kf, sacc[ct], 0, 0, 0);
            }
        }

        // max-free softmax (scale folded into Q); mask inert except at the diagonal
        float p[4][4];
        #pragma unroll
        for (int ct = 0; ct < 4; ct++) {
            int cg = kv0 + ct * 16 + col;
            #pragma unroll
            for (int r = 0; r < 4; r++) {
                float e = __builtin_exp2f(sacc[ct][r]);
                e = (cg > rgb + r) ? 0.f : e;
                p[ct][r] = e;
                l[r] += e;
            }
        }

        // P: C-layout -> wave-private LDS -> A-layout
        #pragma unroll
        for (int ct = 0; ct < 4; ct++)
            #pragma unroll
            for (int r = 0; r < 4; r++)
                Pl[(quad * 4 + r) * 72 + ct * 16 + col] = f2b(p[ct][r]);
        bf16x8 pf[2];
        #pragma unroll
        for (int c = 0; c < 2; c++)
            pf[c] = *(const bf16x8*)&Pl[col * 72 + quad * 8 + c * 32];

        #pragma unroll
        for (int ct = 0; ct < 4; ct++) {
            int h = ct * 16 + col;
            #pragma unroll
            for (int kc = 0; kc < 2; kc++) {
                bf16x8 vf = *(const bf16x8*)&Vl[buf][h * 64 + (((kc * 4 + quad) ^ (col & 7)) << 3)];
                o[ct] = __builtin_amdgcn_mfma_f32_16x16x32_bf16(pf[kc], vf, o[ct], 0, 0, 0);
            }
        }
        buf ^= 1;
    }

    #pragma unroll
    for (int off = 1; off < 16; off <<= 1)
        #pragma unroll
        for (int r = 0; r < 4; r++)
            l[r] += __shfl_xor(l[r], off, 64);

    // bf16 partials: Opart[widx][ct*256 + lane*4 + r]
    const int widx = bid * 8 + wave;
    unsigned short* Op = Opart + (size_t)widx * 1024;
    #pragma unroll
    for (int ct = 0; ct < 4; ct++) {
        ushort4 st;
        st.x = f2b(o[ct][0]); st.y = f2b(o[ct][1]);
        st.z = f2b(o[ct][2]); st.w = f2b(o[ct][3]);
        *(ushort4*)(Op + ct * 256 + lane * 4) = st;
    }
    if (col == 0) {
        #pragma unroll
        for (int r = 0; r < 4; r++)
            Lpart[widx * 16 + quad * 4 + r] = l[r];
    }
}

// ---------- combine split-KV partials: thread layout mirrors attn lanes (coalesced ushort4 reads)
__global__ __launch_bounds__(256) void comb_kernel(const unsigned short* __restrict__ Opart,
                                                   const float* __restrict__ Lpart,
                                                   float* __restrict__ out) {
    const int bid = blockIdx.x;            // 1024 = 4 b x 32 T x 8 wave
    const int b = bid & 3;
    const int T = (bid >> 2) & 31;
    const int wave = bid >> 7;             // 0..7
    const int tid = threadIdx.x;
    const int lane = tid & 63, ct = tid >> 6;
    const int col = lane & 15, quad = lane >> 4;

    const int q = T / 6, r6 = T % 6;
    const int base = (q + 1) * (3 * q + r6);   // piece-id prefix for pieces of <=12 steps
    const int np = (T + 6) / 6;

    float acc[4] = {0.f, 0.f, 0.f, 0.f};
    float l[4] = {0.f, 0.f, 0.f, 0.f};
    for (int p = 0; p < np; p++) {
        int gg = base + p;
        int bidp = ((101 - gg) << 2) | b;
        int widx = bidp * 8 + wave;
        ushort4 v = *(const ushort4*)(Opart + (size_t)widx * 1024 + ct * 256 + lane * 4);
        acc[0] += b2f(v.x); acc[1] += b2f(v.y);
        acc[2] += b2f(v.z); acc[3] += b2f(v.w);
        #pragma unroll
        for (int r = 0; r < 4; r++)
            l[r] += Lpart[widx * 16 + quad * 4 + r];
    }
    const size_t rowb = (size_t)(b << 12) + (T << 7) + wave * 16 + quad * 4;
    #pragma unroll
    for (int r = 0; r < 4; r++)
        out[(rowb + r) * HS + ct * 16 + col] = acc[r] / l[r];
}

extern "C" void kernel_launch(void* const* d_in, const int* in_sizes, int n_in,
                              void* d_out, int out_size, void* d_ws, size_t ws_size,
                              hipStream_t stream) {
    const float* x  = (const float*)d_in[0];
    const float* Wk = (const float*)d_in[1];
    const float* Wq = (const float*)d_in[2];
    const float* Wv = (const float*)d_in[3];
    float* out = (float*)d_out;

    char* ws = (char*)d_ws;
    unsigned short* Wt = (unsigned short*)(ws);                 // 393216 B
    unsigned short* Qb = (unsigned short*)(ws + 393216);        // 2 MiB
    unsigned short* Kb = (unsigned short*)(ws + 2490368);       // 2 MiB
    unsigned short* Vt = (unsigned short*)(ws + 4587520);       // 2 MiB
    unsigned short* Opart = (unsigned short*)(ws + 6684672);    // 408*8*1024*2 = 6.68 MB
    float* Lpart          = (float*)(ws + 13369344);            // 408*8*16*4 = 208896 B

    wt_kernel<<<dim3(768), dim3(256), 0, stream>>>(Wq, Wk, Wv, Wt);
    proj_kernel<<<dim3(512), dim3(256), 0, stream>>>(x, Wt, Qb, Kb, Vt);
    attn_kernel<<<dim3(408), dim3(512), 0, stream>>>(Qb, Kb, Vt, Opart, Lpart);
    comb_kernel<<<dim3(1024), dim3(256), 0, stream>>>(Opart, Lpart, out);
}